// Round 1
// baseline (798.851 us; speedup 1.0000x reference)
//
#include <hip/hip_runtime.h>
#include <stdint.h>

#define N_NODES 100000
#define MT      782
#define MPAD    (MT*128)   // 100096
#define IN_DIM  2048
#define HID     512
#define OUTD    128
#define NG      512
#define LOG2F_  0.69314718055994531f

typedef __attribute__((ext_vector_type(4))) float f32x4;
typedef __attribute__((ext_vector_type(8))) short bf16x8;

typedef const __attribute__((address_space(1))) unsigned int gas_u32;
typedef __attribute__((address_space(3))) unsigned int las_u32;

__device__ __forceinline__ void gload_lds16(const void* g, void* lds) {
  __builtin_amdgcn_global_load_lds((gas_u32*)g, (las_u32*)lds, 16, 0, 0);
}

__device__ __forceinline__ short f2bf(float f) {
  unsigned u = __builtin_bit_cast(unsigned, f);
  u = (u + 0x7fffu + ((u >> 16) & 1u)) >> 16;
  return (short)u;
}
__device__ __forceinline__ float bf2f(short s) {
  unsigned u = ((unsigned)(unsigned short)s) << 16;
  return __builtin_bit_cast(float, u);
}

__device__ __forceinline__ f32x4 mfma16(bf16x8 a, bf16x8 b, f32x4 c) {
  return __builtin_amdgcn_mfma_f32_16x16x32_bf16(a, b, c, 0, 0, 0);
}

// ---------------- prep: transpose+cast weights to bf16 B^T layouts ------------
__global__ void kprep(const float* __restrict__ W1, const float* __restrict__ Wj,
                      const float* __restrict__ W2, const float* __restrict__ W3,
                      const float* __restrict__ ge,
                      short* __restrict__ wcat, short* __restrict__ w2t,
                      short* __restrict__ w3t, short* __restrict__ gencb) {
  const int S1 = 640 * 2048, S2 = 512 * 512, S3 = 128 * 512, S4 = 512 * 128;
  int t = blockIdx.x * 256 + threadIdx.x;
  if (t < S1) {
    int n = t >> 11, k = t & 2047;
    float v = (n < 512) ? W1[(size_t)k * 512 + n] : Wj[(size_t)k * 128 + (n - 512)];
    wcat[t] = f2bf(v);
  } else {
    t -= S1;
    if (t < S2) {
      int n = t >> 9, k = t & 511;
      w2t[t] = f2bf(W2[(size_t)k * 512 + n]);
    } else {
      t -= S2;
      if (t < S3) {
        int n = t >> 9, k = t & 511;
        w3t[t] = f2bf(W3[(size_t)k * 128 + n]);
      } else {
        t -= S3;
        if (t < S4) gencb[t] = f2bf(ge[t]);
      }
    }
  }
}

// ---------------- K1: [feat f32] @ [W1|Wj]^T -> h1 (relu+b1), jump (+b3+bj) ---
__global__ __launch_bounds__(256, 2) void k1(
    const float* __restrict__ feat, const short* __restrict__ wcat,
    const float* __restrict__ b1, const float* __restrict__ b3,
    const float* __restrict__ bj,
    short* __restrict__ h1, short* __restrict__ jmp) {
  __shared__ __align__(16) short As[128 * 32];
  __shared__ __align__(16) short Bs[128 * 32];
  const int bid = blockIdx.x;
  const int mt = bid / 5, nt = bid % 5;
  const int m0 = mt * 128, n0 = nt * 128;
  const int tid = threadIdx.x;
  const int lane = tid & 63, wid = tid >> 6;
  const int wr = wid >> 1, wc = wid & 1;
  const int l16 = lane & 15, lh = lane >> 4;

  f32x4 acc[4][4];
#pragma unroll
  for (int i = 0; i < 4; i++)
#pragma unroll
    for (int j = 0; j < 4; j++) acc[i][j] = (f32x4){0.f, 0.f, 0.f, 0.f};

  const int ar = tid >> 1;
  const int ah = (tid & 1) * 16;
  const bool aok = (m0 + ar) < N_NODES;
  const float* ap = feat + (size_t)(m0 + ar) * IN_DIM + ah;
  const short* bp0 = wcat + (size_t)(n0 + (tid >> 2)) * IN_DIM + (tid & 3) * 8;
  const short* bp1 = bp0 + (size_t)64 * IN_DIM;
  short* adst = &As[ar * 32 + ah];
  short* bdst0 = &Bs[tid * 8];
  short* bdst1 = &Bs[tid * 8 + 2048];

  for (int kt = 0; kt < IN_DIM / 32; ++kt) {
    f32x4 f0, f1, f2, f3;
    if (aok) {
      const f32x4* s = (const f32x4*)(ap + kt * 32);
      f0 = s[0]; f1 = s[1]; f2 = s[2]; f3 = s[3];
    } else {
      f0 = f1 = f2 = f3 = (f32x4){0.f, 0.f, 0.f, 0.f};
    }
    __syncthreads();  // previous iteration's compute done
    bf16x8 s0, s1;
#pragma unroll
    for (int q = 0; q < 4; q++) {
      s0[q] = f2bf(f0[q]); s0[q + 4] = f2bf(f1[q]);
      s1[q] = f2bf(f2[q]); s1[q + 4] = f2bf(f3[q]);
    }
    *(bf16x8*)adst = s0;
    *(bf16x8*)(adst + 8) = s1;
    gload_lds16(bp0 + kt * 32, bdst0);
    gload_lds16(bp1 + kt * 32, bdst1);
    __syncthreads();  // staging complete
    bf16x8 a[4], b[4];
#pragma unroll
    for (int i = 0; i < 4; i++)
      a[i] = *(const bf16x8*)(&As[(wr * 64 + i * 16 + l16) * 32 + lh * 8]);
#pragma unroll
    for (int j = 0; j < 4; j++)
      b[j] = *(const bf16x8*)(&Bs[(wc * 64 + j * 16 + l16) * 32 + lh * 8]);
#pragma unroll
    for (int i = 0; i < 4; i++)
#pragma unroll
      for (int j = 0; j < 4; j++) acc[i][j] = mfma16(a[i], b[j], acc[i][j]);
  }

  if (nt < 4) {
    float bias[4];
#pragma unroll
    for (int j = 0; j < 4; j++) bias[j] = b1[n0 + wc * 64 + j * 16 + l16];
#pragma unroll
    for (int j = 0; j < 4; j++) {
      const int col = n0 + wc * 64 + j * 16 + l16;
#pragma unroll
      for (int i = 0; i < 4; i++) {
        const int row = m0 + wr * 64 + i * 16 + lh * 4;
#pragma unroll
        for (int r = 0; r < 4; r++) {
          float v = acc[i][j][r] + bias[j];
          v = v > 0.f ? v : 0.f;
          h1[(size_t)(row + r) * HID + col] = f2bf(v);
        }
      }
    }
  } else {
    float bias[4];
#pragma unroll
    for (int j = 0; j < 4; j++) {
      int c = wc * 64 + j * 16 + l16;
      bias[j] = b3[c] + bj[c];
    }
#pragma unroll
    for (int j = 0; j < 4; j++) {
      const int c = wc * 64 + j * 16 + l16;
#pragma unroll
      for (int i = 0; i < 4; i++) {
        const int row = m0 + wr * 64 + i * 16 + lh * 4;
#pragma unroll
        for (int r = 0; r < 4; r++)
          jmp[(size_t)(row + r) * OUTD + c] = f2bf(acc[i][j][r] + bias[j]);
      }
    }
  }
}

// ---------------- K2: h1 @ W2^T -> h2 (relu+b2) -------------------------------
__global__ __launch_bounds__(256, 2) void k2(
    const short* __restrict__ h1, const short* __restrict__ w2t,
    const float* __restrict__ b2, short* __restrict__ h2) {
  __shared__ __align__(16) short As[128 * 32];
  __shared__ __align__(16) short Bs[128 * 32];
  const int bid = blockIdx.x;
  const int mt = bid >> 2, nt = bid & 3;
  const int m0 = mt * 128, n0 = nt * 128;
  const int tid = threadIdx.x;
  const int lane = tid & 63, wid = tid >> 6;
  const int wr = wid >> 1, wc = wid & 1;
  const int l16 = lane & 15, lh = lane >> 4;

  f32x4 acc[4][4];
#pragma unroll
  for (int i = 0; i < 4; i++)
#pragma unroll
    for (int j = 0; j < 4; j++) acc[i][j] = (f32x4){0.f, 0.f, 0.f, 0.f};

  const short* ap0 = h1 + (size_t)(m0 + (tid >> 2)) * HID + (tid & 3) * 8;
  const short* ap1 = ap0 + (size_t)64 * HID;
  const short* bp0 = w2t + (size_t)(n0 + (tid >> 2)) * HID + (tid & 3) * 8;
  const short* bp1 = bp0 + (size_t)64 * HID;

  for (int kt = 0; kt < HID / 32; ++kt) {
    __syncthreads();
    gload_lds16(ap0 + kt * 32, &As[tid * 8]);
    gload_lds16(ap1 + kt * 32, &As[tid * 8 + 2048]);
    gload_lds16(bp0 + kt * 32, &Bs[tid * 8]);
    gload_lds16(bp1 + kt * 32, &Bs[tid * 8 + 2048]);
    __syncthreads();
    bf16x8 a[4], b[4];
#pragma unroll
    for (int i = 0; i < 4; i++)
      a[i] = *(const bf16x8*)(&As[(wr * 64 + i * 16 + l16) * 32 + lh * 8]);
#pragma unroll
    for (int j = 0; j < 4; j++)
      b[j] = *(const bf16x8*)(&Bs[(wc * 64 + j * 16 + l16) * 32 + lh * 8]);
#pragma unroll
    for (int i = 0; i < 4; i++)
#pragma unroll
      for (int j = 0; j < 4; j++) acc[i][j] = mfma16(a[i], b[j], acc[i][j]);
  }

  float bias[4];
#pragma unroll
  for (int j = 0; j < 4; j++) bias[j] = b2[n0 + wc * 64 + j * 16 + l16];
#pragma unroll
  for (int j = 0; j < 4; j++) {
    const int col = n0 + wc * 64 + j * 16 + l16;
#pragma unroll
    for (int i = 0; i < 4; i++) {
      const int row = m0 + wr * 64 + i * 16 + lh * 4;
#pragma unroll
      for (int r = 0; r < 4; r++) {
        float v = acc[i][j][r] + bias[j];
        v = v > 0.f ? v : 0.f;
        h2[(size_t)(row + r) * HID + col] = f2bf(v);
      }
    }
  }
}

// ---------------- K3: l_enc = h2@W3^T + jump; res = l_enc@g_enc^T; JS loss ----
__global__ __launch_bounds__(256, 2) void k3(
    const short* __restrict__ h2, const short* __restrict__ w3t,
    const short* __restrict__ jmp, const short* __restrict__ genc,
    const int* __restrict__ gid, float* __restrict__ partials) {
  __shared__ __align__(16) short As[128 * 32];
  __shared__ __align__(16) short Bs[128 * 32];
  __shared__ __align__(16) short Ll[128 * 128];  // l_enc, XOR-swizzled rows
  __shared__ int gids[128];
  __shared__ float sred[8];
  const int mt = blockIdx.x;
  const int m0 = mt * 128;
  const int tid = threadIdx.x;
  const int lane = tid & 63, wid = tid >> 6;
  const int wr = wid >> 1, wc = wid & 1;
  const int l16 = lane & 15, lh = lane >> 4;

  if (tid < 128) {
    int r = m0 + tid;
    gids[tid] = (r < N_NODES) ? gid[r] : -1;
  }

  f32x4 acc[4][4];
#pragma unroll
  for (int i = 0; i < 4; i++)
#pragma unroll
    for (int j = 0; j < 4; j++) acc[i][j] = (f32x4){0.f, 0.f, 0.f, 0.f};

  const short* ap0 = h2 + (size_t)(m0 + (tid >> 2)) * HID + (tid & 3) * 8;
  const short* ap1 = ap0 + (size_t)64 * HID;
  const short* bp0 = w3t + (size_t)(tid >> 2) * HID + (tid & 3) * 8;
  const short* bp1 = bp0 + (size_t)64 * HID;

  for (int kt = 0; kt < HID / 32; ++kt) {
    __syncthreads();
    gload_lds16(ap0 + kt * 32, &As[tid * 8]);
    gload_lds16(ap1 + kt * 32, &As[tid * 8 + 2048]);
    gload_lds16(bp0 + kt * 32, &Bs[tid * 8]);
    gload_lds16(bp1 + kt * 32, &Bs[tid * 8 + 2048]);
    __syncthreads();
    bf16x8 a[4], b[4];
#pragma unroll
    for (int i = 0; i < 4; i++)
      a[i] = *(const bf16x8*)(&As[(wr * 64 + i * 16 + l16) * 32 + lh * 8]);
#pragma unroll
    for (int j = 0; j < 4; j++)
      b[j] = *(const bf16x8*)(&Bs[(wc * 64 + j * 16 + l16) * 32 + lh * 8]);
#pragma unroll
    for (int i = 0; i < 4; i++)
#pragma unroll
      for (int j = 0; j < 4; j++) acc[i][j] = mfma16(a[i], b[j], acc[i][j]);
  }

  // epilogue: l_enc = acc + jump (jump already holds b3+bj) -> Ll (swizzled bf16)
#pragma unroll
  for (int j = 0; j < 4; j++) {
    const int col = wc * 64 + j * 16 + l16;
#pragma unroll
    for (int i = 0; i < 4; i++) {
      const int rowb = wr * 64 + i * 16 + lh * 4;
#pragma unroll
      for (int r = 0; r < 4; r++) {
        const int row = rowb + r;
        float v = acc[i][j][r] + bf2f(jmp[(size_t)(m0 + row) * OUTD + col]);
        unsigned byte = (unsigned)row * 256u +
                        (((unsigned)col * 2u) ^ (((unsigned)(row & 7)) << 4));
        *(short*)((char*)Ll + byte) = f2bf(v);
      }
    }
  }
  __syncthreads();

  int myg[4][4];
#pragma unroll
  for (int i = 0; i < 4; i++)
#pragma unroll
    for (int r = 0; r < 4; r++) myg[i][r] = gids[wr * 64 + i * 16 + lh * 4 + r];

  float pacc = 0.f, nacc = 0.f;
  for (int nc = 0; nc < 4; ++nc) {
    f32x4 a2[4][4];
#pragma unroll
    for (int i = 0; i < 4; i++)
#pragma unroll
      for (int j = 0; j < 4; j++) a2[i][j] = (f32x4){0.f, 0.f, 0.f, 0.f};
#pragma unroll
    for (int ks = 0; ks < 4; ++ks) {
      bf16x8 af[4], bg[4];
#pragma unroll
      for (int i = 0; i < 4; i++) {
        const int row = wr * 64 + i * 16 + l16;
        unsigned byte = (unsigned)row * 256u +
                        (((unsigned)(ks * 64 + lh * 16)) ^ (((unsigned)(row & 7)) << 4));
        af[i] = *(const bf16x8*)((const char*)Ll + byte);
      }
#pragma unroll
      for (int j = 0; j < 4; j++) {
        const int g = nc * 128 + wc * 64 + j * 16 + l16;
        bg[j] = *(const bf16x8*)(genc + (size_t)g * OUTD + ks * 32 + lh * 8);
      }
#pragma unroll
      for (int i = 0; i < 4; i++)
#pragma unroll
        for (int j = 0; j < 4; j++) a2[i][j] = mfma16(af[i], bg[j], a2[i][j]);
    }
#pragma unroll
    for (int j = 0; j < 4; j++) {
      const int g = nc * 128 + wc * 64 + j * 16 + l16;
#pragma unroll
      for (int i = 0; i < 4; i++) {
#pragma unroll
        for (int r = 0; r < 4; r++) {
          float rv = a2[i][j][r];
          int gr = myg[i][r];
          float t = __expf(-fabsf(rv));
          float lg = __logf(1.f + t);
          if (gr == g)
            pacc += LOG2F_ - (fmaxf(-rv, 0.f) + lg);
          else if (gr >= 0)
            nacc += (fmaxf(rv, 0.f) + lg) - LOG2F_;
        }
      }
    }
  }

#pragma unroll
  for (int o = 32; o; o >>= 1) {
    pacc += __shfl_down(pacc, o);
    nacc += __shfl_down(nacc, o);
  }
  if (lane == 0) { sred[wid] = pacc; sred[4 + wid] = nacc; }
  __syncthreads();
  if (tid == 0) {
    partials[2 * mt] = sred[0] + sred[1] + sred[2] + sred[3];
    partials[2 * mt + 1] = sred[4] + sred[5] + sred[6] + sred[7];
  }
}

// ---------------- K4: deterministic final reduction ---------------------------
__global__ void k4(const float* __restrict__ partials, float* __restrict__ out) {
  const int tid = threadIdx.x;
  float p = 0.f, n = 0.f;
  for (int i = tid; i < MT; i += 256) {
    p += partials[2 * i];
    n += partials[2 * i + 1];
  }
#pragma unroll
  for (int o = 32; o; o >>= 1) {
    p += __shfl_down(p, o);
    n += __shfl_down(n, o);
  }
  __shared__ float sp[4], sn[4];
  const int wid = tid >> 6, lane = tid & 63;
  if (lane == 0) { sp[wid] = p; sn[wid] = n; }
  __syncthreads();
  if (tid == 0) {
    float P = sp[0] + sp[1] + sp[2] + sp[3];
    float Nn = sn[0] + sn[1] + sn[2] + sn[3];
    out[0] = Nn / (100000.0f * 511.0f) - P / 100000.0f;
  }
}

extern "C" void kernel_launch(void* const* d_in, const int* in_sizes, int n_in,
                              void* d_out, int out_size, void* d_ws, size_t ws_size,
                              hipStream_t stream) {
  const float* feat = (const float*)d_in[0];
  const float* genc_f = (const float*)d_in[1];
  const int* gid = (const int*)d_in[2];
  const float* W1 = (const float*)d_in[3];
  const float* b1 = (const float*)d_in[4];
  const float* W2 = (const float*)d_in[5];
  const float* b2 = (const float*)d_in[6];
  const float* W3 = (const float*)d_in[7];
  const float* b3 = (const float*)d_in[8];
  const float* Wj = (const float*)d_in[9];
  const float* bj = (const float*)d_in[10];
  float* out = (float*)d_out;

  char* ws = (char*)d_ws;
  float* partials = (float*)ws;                       // 782*2 f32
  short* wcat = (short*)(ws + 8192);                  // [640][2048] bf16
  short* w2t = wcat + (size_t)640 * 2048;             // [512][512]
  short* w3t = w2t + (size_t)512 * 512;               // [128][512]
  short* gencb = w3t + (size_t)128 * 512;             // [512][128]
  short* h1 = gencb + (size_t)512 * 128;              // [MPAD][512]
  short* h2 = h1 + (size_t)MPAD * 512;                // [MPAD][512]
  short* jmp = h2 + (size_t)MPAD * 512;               // [MPAD][128]

  kprep<<<6656, 256, 0, stream>>>(W1, Wj, W2, W3, genc_f, wcat, w2t, w3t, gencb);
  k1<<<MT * 5, 256, 0, stream>>>(feat, wcat, b1, b3, bj, h1, jmp);
  k2<<<MT * 4, 256, 0, stream>>>(h1, w2t, b2, h2);
  k3<<<MT, 256, 0, stream>>>(h2, w3t, jmp, gencb, gid, partials);
  k4<<<1, 256, 0, stream>>>(partials, out);
}

// Round 2
// 680.278 us; speedup vs baseline: 1.1743x; 1.1743x over previous
//
#include <hip/hip_runtime.h>
#include <stdint.h>

#define N_NODES 100000
#define MT      782          // 128-row tiles (k3)
#define MT64    1564         // 64-row tiles (k1,k2)
#define MPAD    (MT*128)     // 100096
#define IN_DIM  2048
#define HID     512
#define OUTD    128
#define NG      512
#define LOG2F_  0.69314718055994531f

typedef __attribute__((ext_vector_type(4))) float f32x4;
typedef __attribute__((ext_vector_type(8))) short bf16x8;
typedef __attribute__((ext_vector_type(4))) short bf16x4;

typedef const __attribute__((address_space(1))) unsigned int gas_u32;
typedef __attribute__((address_space(3))) unsigned int las_u32;

__device__ __forceinline__ void gload_lds16(const void* g, void* lds) {
  __builtin_amdgcn_global_load_lds((gas_u32*)g, (las_u32*)lds, 16, 0, 0);
}

__device__ __forceinline__ short f2bf(float f) {
  unsigned u = __builtin_bit_cast(unsigned, f);
  u = (u + 0x7fffu + ((u >> 16) & 1u)) >> 16;
  return (short)u;
}
__device__ __forceinline__ float bf2f(short s) {
  unsigned u = ((unsigned)(unsigned short)s) << 16;
  return __builtin_bit_cast(float, u);
}

__device__ __forceinline__ f32x4 mfma16(bf16x8 a, bf16x8 b, f32x4 c) {
  return __builtin_amdgcn_mfma_f32_16x16x32_bf16(a, b, c, 0, 0, 0);
}

// ---------------- prep: transpose+cast weights to bf16 B^T layouts ------------
__global__ void kprep(const float* __restrict__ W1, const float* __restrict__ Wj,
                      const float* __restrict__ W2, const float* __restrict__ W3,
                      const float* __restrict__ ge,
                      short* __restrict__ wcat, short* __restrict__ w2t,
                      short* __restrict__ w3t, short* __restrict__ gencb) {
  const int S1 = 640 * 2048, S2 = 512 * 512, S3 = 128 * 512, S4 = 512 * 128;
  int t = blockIdx.x * 256 + threadIdx.x;
  if (t < S1) {
    int n = t >> 11, k = t & 2047;
    float v = (n < 512) ? W1[(size_t)k * 512 + n] : Wj[(size_t)k * 128 + (n - 512)];
    wcat[t] = f2bf(v);
  } else {
    t -= S1;
    if (t < S2) {
      int n = t >> 9, k = t & 511;
      w2t[t] = f2bf(W2[(size_t)k * 512 + n]);
    } else {
      t -= S2;
      if (t < S3) {
        int n = t >> 9, k = t & 511;
        w3t[t] = f2bf(W3[(size_t)k * 128 + n]);
      } else {
        t -= S3;
        if (t < S4) gencb[t] = f2bf(ge[t]);
      }
    }
  }
}

// ---- K1: feat(f32)[64 rows] @ [W1|Wj]^T(640) -> h1 (relu+b1), jump (+b3+bj) --
// Full N per block: feat is fetched from HBM exactly once.
__global__ __launch_bounds__(512, 4) void k1(
    const float* __restrict__ feat, const short* __restrict__ wcat,
    const float* __restrict__ b1, const float* __restrict__ b3,
    const float* __restrict__ bj,
    short* __restrict__ h1, short* __restrict__ jmp) {
  __shared__ __align__(16) short As[64 * 32];    // 4 KB
  __shared__ __align__(16) short Bs[640 * 32];   // 40 KB
  const int tid = threadIdx.x;
  const int lane = tid & 63, w = tid >> 6;       // 8 waves, 1M x 8N
  const int l16 = lane & 15, lh = lane >> 4;
  const int m0 = blockIdx.x * 64;

  f32x4 acc[4][5];
#pragma unroll
  for (int m = 0; m < 4; m++)
#pragma unroll
    for (int n = 0; n < 5; n++) acc[m][n] = (f32x4){0.f, 0.f, 0.f, 0.f};

  // A staging: thread t loads f32x4 of row (t>>3), cols (t&7)*4 .. +4
  const int arow = tid >> 3, acol = (tid & 7) * 4;
  const bool aok = (m0 + arow) < N_NODES;
  const float* ap = feat + (size_t)(m0 + arow) * IN_DIM + acol;
  short* adst = &As[arow * 32 + acol];

  // B staging: 5 x gload_lds16 per thread (rows (t>>2)+128s)
  const short* bp = wcat + (size_t)(tid >> 2) * IN_DIM + (tid & 3) * 8;
  short* bdst = &Bs[(size_t)(tid >> 2) * 32 + (tid & 3) * 8];

  f32x4 aval = aok ? *(const f32x4*)ap : (f32x4){0.f, 0.f, 0.f, 0.f};

  for (int kt = 0; kt < IN_DIM / 32; ++kt) {
    __syncthreads();  // previous compute done, LDS writable
    bf16x4 av;
#pragma unroll
    for (int q = 0; q < 4; q++) av[q] = f2bf(aval[q]);
    *(bf16x4*)adst = av;
#pragma unroll
    for (int s = 0; s < 5; s++)
      gload_lds16(bp + (size_t)(128 * s) * IN_DIM + kt * 32, bdst + 128 * s * 32);
    __syncthreads();  // staging visible
    if (kt < IN_DIM / 32 - 1)
      aval = aok ? *(const f32x4*)(ap + (kt + 1) * 32) : (f32x4){0.f, 0.f, 0.f, 0.f};
    bf16x8 a[4], b[5];
#pragma unroll
    for (int m = 0; m < 4; m++)
      a[m] = *(const bf16x8*)(&As[(m * 16 + l16) * 32 + lh * 8]);
#pragma unroll
    for (int n = 0; n < 5; n++)
      b[n] = *(const bf16x8*)(&Bs[(w * 80 + n * 16 + l16) * 32 + lh * 8]);
#pragma unroll
    for (int m = 0; m < 4; m++)
#pragma unroll
      for (int n = 0; n < 5; n++) acc[m][n] = mfma16(a[m], b[n], acc[m][n]);
  }

#pragma unroll
  for (int n = 0; n < 5; n++) {
    const int c = w * 80 + n * 16 + l16;   // fragment lies entirely on one side of 512
    if (c < 512) {
      const float bias = b1[c];
#pragma unroll
      for (int m = 0; m < 4; m++) {
        const int row = m0 + m * 16 + lh * 4;
#pragma unroll
        for (int r = 0; r < 4; r++) {
          float v = acc[m][n][r] + bias;
          v = v > 0.f ? v : 0.f;
          h1[(size_t)(row + r) * HID + c] = f2bf(v);
        }
      }
    } else {
      const int cj = c - 512;
      const float bias = b3[cj] + bj[cj];
#pragma unroll
      for (int m = 0; m < 4; m++) {
        const int row = m0 + m * 16 + lh * 4;
#pragma unroll
        for (int r = 0; r < 4; r++)
          jmp[(size_t)(row + r) * OUTD + cj] = f2bf(acc[m][n][r] + bias);
      }
    }
  }
}

// ---------------- K2: h1[64 rows] @ W2^T (full N=512) -> h2 (relu+b2) ---------
__global__ __launch_bounds__(512, 4) void k2(
    const short* __restrict__ h1, const short* __restrict__ w2t,
    const float* __restrict__ b2, short* __restrict__ h2) {
  __shared__ __align__(16) short As[64 * 32];    // 4 KB
  __shared__ __align__(16) short Bs[512 * 32];   // 32 KB
  const int tid = threadIdx.x;
  const int lane = tid & 63, w = tid >> 6;       // 8 waves, 1M x 8N
  const int l16 = lane & 15, lh = lane >> 4;
  const int m0 = blockIdx.x * 64;

  f32x4 acc[4][4];
#pragma unroll
  for (int m = 0; m < 4; m++)
#pragma unroll
    for (int n = 0; n < 4; n++) acc[m][n] = (f32x4){0.f, 0.f, 0.f, 0.f};

  const short* apg = h1 + (size_t)(m0 + (tid >> 2)) * HID + (tid & 3) * 8;  // tid<256
  short* adst = &As[tid * 8];
  const short* bpg = w2t + (size_t)(tid >> 2) * HID + (tid & 3) * 8;
  short* bdst = &Bs[(size_t)(tid >> 2) * 32 + (tid & 3) * 8];

  for (int kt = 0; kt < HID / 32; ++kt) {
    __syncthreads();
    if (tid < 256) gload_lds16(apg + kt * 32, adst);
#pragma unroll
    for (int s = 0; s < 4; s++)
      gload_lds16(bpg + (size_t)(128 * s) * HID + kt * 32, bdst + 128 * s * 32);
    __syncthreads();
    bf16x8 a[4], b[4];
#pragma unroll
    for (int m = 0; m < 4; m++)
      a[m] = *(const bf16x8*)(&As[(m * 16 + l16) * 32 + lh * 8]);
#pragma unroll
    for (int n = 0; n < 4; n++)
      b[n] = *(const bf16x8*)(&Bs[(w * 64 + n * 16 + l16) * 32 + lh * 8]);
#pragma unroll
    for (int m = 0; m < 4; m++)
#pragma unroll
      for (int n = 0; n < 4; n++) acc[m][n] = mfma16(a[m], b[n], acc[m][n]);
  }

#pragma unroll
  for (int n = 0; n < 4; n++) {
    const int c = w * 64 + n * 16 + l16;
    const float bias = b2[c];
#pragma unroll
    for (int m = 0; m < 4; m++) {
      const int row = m0 + m * 16 + lh * 4;
#pragma unroll
      for (int r = 0; r < 4; r++) {
        float v = acc[m][n][r] + bias;
        v = v > 0.f ? v : 0.f;
        h2[(size_t)(row + r) * HID + c] = f2bf(v);
      }
    }
  }
}

// ---------------- K3: l_enc = h2@W3^T + jump; res = l_enc@g_enc^T; JS loss ----
__global__ __launch_bounds__(256, 2) void k3(
    const short* __restrict__ h2, const short* __restrict__ w3t,
    const short* __restrict__ jmp, const short* __restrict__ genc,
    const int* __restrict__ gid, float* __restrict__ partials) {
  __shared__ __align__(16) short As[128 * 32];
  __shared__ __align__(16) short Bs[128 * 32];
  __shared__ __align__(16) short Ll[128 * 128];  // l_enc, XOR-swizzled rows
  __shared__ int gids[128];
  __shared__ float sred[8];
  const int mt = blockIdx.x;
  const int m0 = mt * 128;
  const int tid = threadIdx.x;
  const int lane = tid & 63, wid = tid >> 6;
  const int wr = wid >> 1, wc = wid & 1;
  const int l16 = lane & 15, lh = lane >> 4;

  if (tid < 128) {
    int r = m0 + tid;
    gids[tid] = (r < N_NODES) ? gid[r] : -1;
  }

  f32x4 acc[4][4];
#pragma unroll
  for (int i = 0; i < 4; i++)
#pragma unroll
    for (int j = 0; j < 4; j++) acc[i][j] = (f32x4){0.f, 0.f, 0.f, 0.f};

  const short* ap0 = h2 + (size_t)(m0 + (tid >> 2)) * HID + (tid & 3) * 8;
  const short* ap1 = ap0 + (size_t)64 * HID;
  const short* bp0 = w3t + (size_t)(tid >> 2) * HID + (tid & 3) * 8;
  const short* bp1 = bp0 + (size_t)64 * HID;

  for (int kt = 0; kt < HID / 32; ++kt) {
    __syncthreads();
    gload_lds16(ap0 + kt * 32, &As[tid * 8]);
    gload_lds16(ap1 + kt * 32, &As[tid * 8 + 2048]);
    gload_lds16(bp0 + kt * 32, &Bs[tid * 8]);
    gload_lds16(bp1 + kt * 32, &Bs[tid * 8 + 2048]);
    __syncthreads();
    bf16x8 a[4], b[4];
#pragma unroll
    for (int i = 0; i < 4; i++)
      a[i] = *(const bf16x8*)(&As[(wr * 64 + i * 16 + l16) * 32 + lh * 8]);
#pragma unroll
    for (int j = 0; j < 4; j++)
      b[j] = *(const bf16x8*)(&Bs[(wc * 64 + j * 16 + l16) * 32 + lh * 8]);
#pragma unroll
    for (int i = 0; i < 4; i++)
#pragma unroll
      for (int j = 0; j < 4; j++) acc[i][j] = mfma16(a[i], b[j], acc[i][j]);
  }

  // epilogue: l_enc = acc + jump (jump already holds b3+bj) -> Ll (swizzled bf16)
#pragma unroll
  for (int j = 0; j < 4; j++) {
    const int col = wc * 64 + j * 16 + l16;
#pragma unroll
    for (int i = 0; i < 4; i++) {
      const int rowb = wr * 64 + i * 16 + lh * 4;
#pragma unroll
      for (int r = 0; r < 4; r++) {
        const int row = rowb + r;
        float v = acc[i][j][r] + bf2f(jmp[(size_t)(m0 + row) * OUTD + col]);
        unsigned byte = (unsigned)row * 256u +
                        (((unsigned)col * 2u) ^ (((unsigned)(row & 7)) << 4));
        *(short*)((char*)Ll + byte) = f2bf(v);
      }
    }
  }
  __syncthreads();

  int myg[4][4];
#pragma unroll
  for (int i = 0; i < 4; i++)
#pragma unroll
    for (int r = 0; r < 4; r++) myg[i][r] = gids[wr * 64 + i * 16 + lh * 4 + r];

  float pacc = 0.f, nacc = 0.f;
  for (int nc = 0; nc < 4; ++nc) {
    f32x4 a2[4][4];
#pragma unroll
    for (int i = 0; i < 4; i++)
#pragma unroll
      for (int j = 0; j < 4; j++) a2[i][j] = (f32x4){0.f, 0.f, 0.f, 0.f};
#pragma unroll
    for (int ks = 0; ks < 4; ++ks) {
      bf16x8 af[4], bg[4];
#pragma unroll
      for (int i = 0; i < 4; i++) {
        const int row = wr * 64 + i * 16 + l16;
        unsigned byte = (unsigned)row * 256u +
                        (((unsigned)(ks * 64 + lh * 16)) ^ (((unsigned)(row & 7)) << 4));
        af[i] = *(const bf16x8*)((const char*)Ll + byte);
      }
#pragma unroll
      for (int j = 0; j < 4; j++) {
        const int g = nc * 128 + wc * 64 + j * 16 + l16;
        bg[j] = *(const bf16x8*)(genc + (size_t)g * OUTD + ks * 32 + lh * 8);
      }
#pragma unroll
      for (int i = 0; i < 4; i++)
#pragma unroll
        for (int j = 0; j < 4; j++) a2[i][j] = mfma16(af[i], bg[j], a2[i][j]);
    }
#pragma unroll
    for (int j = 0; j < 4; j++) {
      const int g = nc * 128 + wc * 64 + j * 16 + l16;
#pragma unroll
      for (int i = 0; i < 4; i++) {
#pragma unroll
        for (int r = 0; r < 4; r++) {
          float rv = a2[i][j][r];
          int gr = myg[i][r];
          float t = __expf(-fabsf(rv));
          float lg = __logf(1.f + t);
          if (gr == g)
            pacc += LOG2F_ - (fmaxf(-rv, 0.f) + lg);
          else if (gr >= 0)
            nacc += (fmaxf(rv, 0.f) + lg) - LOG2F_;
        }
      }
    }
  }

#pragma unroll
  for (int o = 32; o; o >>= 1) {
    pacc += __shfl_down(pacc, o);
    nacc += __shfl_down(nacc, o);
  }
  if (lane == 0) { sred[wid] = pacc; sred[4 + wid] = nacc; }
  __syncthreads();
  if (tid == 0) {
    partials[2 * mt] = sred[0] + sred[1] + sred[2] + sred[3];
    partials[2 * mt + 1] = sred[4] + sred[5] + sred[6] + sred[7];
  }
}

// ---------------- K4: deterministic final reduction ---------------------------
__global__ void k4(const float* __restrict__ partials, float* __restrict__ out) {
  const int tid = threadIdx.x;
  float p = 0.f, n = 0.f;
  for (int i = tid; i < MT; i += 256) {
    p += partials[2 * i];
    n += partials[2 * i + 1];
  }
#pragma unroll
  for (int o = 32; o; o >>= 1) {
    p += __shfl_down(p, o);
    n += __shfl_down(n, o);
  }
  __shared__ float sp[4], sn[4];
  const int wid = tid >> 6, lane = tid & 63;
  if (lane == 0) { sp[wid] = p; sn[wid] = n; }
  __syncthreads();
  if (tid == 0) {
    float P = sp[0] + sp[1] + sp[2] + sp[3];
    float Nn = sn[0] + sn[1] + sn[2] + sn[3];
    out[0] = Nn / (100000.0f * 511.0f) - P / 100000.0f;
  }
}

extern "C" void kernel_launch(void* const* d_in, const int* in_sizes, int n_in,
                              void* d_out, int out_size, void* d_ws, size_t ws_size,
                              hipStream_t stream) {
  const float* feat = (const float*)d_in[0];
  const float* genc_f = (const float*)d_in[1];
  const int* gid = (const int*)d_in[2];
  const float* W1 = (const float*)d_in[3];
  const float* b1 = (const float*)d_in[4];
  const float* W2 = (const float*)d_in[5];
  const float* b2 = (const float*)d_in[6];
  const float* W3 = (const float*)d_in[7];
  const float* b3 = (const float*)d_in[8];
  const float* Wj = (const float*)d_in[9];
  const float* bj = (const float*)d_in[10];
  float* out = (float*)d_out;

  char* ws = (char*)d_ws;
  float* partials = (float*)ws;                       // 782*2 f32
  short* wcat = (short*)(ws + 8192);                  // [640][2048] bf16
  short* w2t = wcat + (size_t)640 * 2048;             // [512][512]
  short* w3t = w2t + (size_t)512 * 512;               // [128][512]
  short* gencb = w3t + (size_t)128 * 512;             // [512][128]
  short* h1 = gencb + (size_t)512 * 128;              // [MPAD][512]
  short* h2 = h1 + (size_t)MPAD * 512;                // [MPAD][512]
  short* jmp = h2 + (size_t)MPAD * 512;               // [MPAD][128]

  kprep<<<6656, 256, 0, stream>>>(W1, Wj, W2, W3, genc_f, wcat, w2t, w3t, gencb);
  k1<<<MT64, 512, 0, stream>>>(feat, wcat, b1, b3, bj, h1, jmp);
  k2<<<MT64, 512, 0, stream>>>(h1, w2t, b2, h2);
  k3<<<MT, 256, 0, stream>>>(h2, w3t, jmp, gencb, gid, partials);
  k4<<<1, 256, 0, stream>>>(partials, out);
}